// Round 1
// baseline (217.668 us; speedup 1.0000x reference)
//
#include <hip/hip_runtime.h>
#include <hip/hip_bf16.h>

// ---------------------------------------------------------------------------
// total = CE(pred, labels)
//       + 0.05 * MSE(recon, data)
//       + 0.05 * sum_{j<k} max(0, 1 - ||p_j - p_k||)^2
//       + 0.05 * sum_p min_b dist(e_b, p) / P
//       + 0.05 * sum_b min_p dist(e_b, p) / B
// dist via ||x||^2 + ||y||^2 - 2 x.y, clipped at 1e-12, sqrt.
// ---------------------------------------------------------------------------

constexpr float FEPS = 1e-12f;
constexpr float DMIN = 1.0f;

// ---------------- CE: one wave per row (C=100 <= 128) ----------------------
__global__ __launch_bounds__(256) void ce_kernel(const float* __restrict__ pred,
                                                 const int* __restrict__ lab,
                                                 float* __restrict__ ce_out,
                                                 int B, int C, int rows_per_wave) {
    int lane = threadIdx.x & 63;
    int w    = threadIdx.x >> 6;
    int wid  = blockIdx.x * 4 + w;
    float acc = 0.f;
    for (int i = 0; i < rows_per_wave; ++i) {
        int row = wid * rows_per_wave + i;
        if (row >= B) break;
        const float* p = pred + (size_t)row * C;
        float v1 = (lane < C)      ? p[lane]      : -3.0e38f;
        float v2 = (lane + 64 < C) ? p[lane + 64] : -3.0e38f;
        float m = fmaxf(v1, v2);
        #pragma unroll
        for (int o = 32; o; o >>= 1) m = fmaxf(m, __shfl_xor(m, o));
        float s = ((lane < C) ? __expf(v1 - m) : 0.f)
                + ((lane + 64 < C) ? __expf(v2 - m) : 0.f);
        #pragma unroll
        for (int o = 32; o; o >>= 1) s += __shfl_xor(s, o);
        float lv = p[lab[row]];
        acc += m + __logf(s) - lv;
    }
    __shared__ float sred[4];
    if (lane == 0) sred[w] = acc;
    __syncthreads();
    if (threadIdx.x == 0) atomicAdd(ce_out, sred[0] + sred[1] + sred[2] + sred[3]);
}

// ---------------- MSE: float4 grid-stride ----------------------------------
__global__ __launch_bounds__(256) void mse_kernel(const float4* __restrict__ r,
                                                  const float4* __restrict__ d,
                                                  float* __restrict__ out, int n4) {
    int idx    = blockIdx.x * blockDim.x + threadIdx.x;
    int stride = gridDim.x * blockDim.x;
    float acc = 0.f;
    for (int i = idx; i < n4; i += stride) {
        float4 a = r[i], b = d[i];
        float dx = a.x - b.x, dy = a.y - b.y, dz = a.z - b.z, dw = a.w - b.w;
        acc = fmaf(dx, dx, acc);
        acc = fmaf(dy, dy, acc);
        acc = fmaf(dz, dz, acc);
        acc = fmaf(dw, dw, acc);
    }
    #pragma unroll
    for (int o = 32; o; o >>= 1) acc += __shfl_xor(acc, o);
    __shared__ float sred[4];
    int lane = threadIdx.x & 63, w = threadIdx.x >> 6;
    if (lane == 0) sred[w] = acc;
    __syncthreads();
    if (threadIdx.x == 0) atomicAdd(out, sred[0] + sred[1] + sred[2] + sred[3]);
}

// ---------------- Prototype diversity + norms ------------------------------
// block p (P blocks, P threads). Thread q computes dot(p,q) and dot(q,q).
__global__ __launch_bounds__(128) void div_kernel(const float* __restrict__ proto,
                                                  float* __restrict__ div_out,
                                                  float* __restrict__ pnorm,
                                                  int P, int dd) {
    __shared__ float pp[1024];
    __shared__ float spp;
    int p = blockIdx.x, q = threadIdx.x;
    for (int k = q; k < dd; k += blockDim.x) pp[k] = proto[(size_t)p * dd + k];
    __syncthreads();
    const float4* pq4 = (const float4*)(proto + (size_t)q * dd);
    const float4* pp4 = (const float4*)pp;
    float dot = 0.f, qq = 0.f;
    for (int k4 = 0; k4 < dd / 4; ++k4) {
        float4 v = pq4[k4];
        float4 u = pp4[k4];
        dot = fmaf(u.x, v.x, dot); dot = fmaf(u.y, v.y, dot);
        dot = fmaf(u.z, v.z, dot); dot = fmaf(u.w, v.w, dot);
        qq  = fmaf(v.x, v.x, qq);  qq  = fmaf(v.y, v.y, qq);
        qq  = fmaf(v.z, v.z, qq);  qq  = fmaf(v.w, v.w, qq);
    }
    if (p == 0) pnorm[q] = qq;
    if (q == p) spp = qq;
    __syncthreads();
    float h2 = 0.f;
    if (q > p) {
        float sq = spp + qq - 2.f * dot;
        float dist = sqrtf(fmaxf(sq, FEPS));
        float h = fmaxf(0.f, DMIN - dist);
        h2 = h * h;
    }
    #pragma unroll
    for (int o = 32; o; o >>= 1) h2 += __shfl_xor(h2, o);
    __shared__ float sred[2];
    if ((threadIdx.x & 63) == 0) sred[threadIdx.x >> 6] = h2;
    __syncthreads();
    if (threadIdx.x == 0) atomicAdd(div_out, sred[0] + sred[1]);
}

// ---------------- dist GEMM + row/col mins ---------------------------------
// Tile: 64 rows x 128 protos, K-chunks of 32. 256 threads, 4x8 acc/thread.
#define BM 64
#define BK 32
__global__ __launch_bounds__(256) void dist_kernel(const float* __restrict__ emb,
                                                   const float* __restrict__ proto,
                                                   const float* __restrict__ pnorm,
                                                   unsigned* __restrict__ proto_min,
                                                   float* __restrict__ cov_out,
                                                   int dd) {
    __shared__ float    As[BM][36];     // padded to avoid bank conflicts
    __shared__ float    Bs[BK][132];    // [kk][p], padded
    __shared__ float    rown[BM];
    __shared__ unsigned colmin[128];
    __shared__ unsigned covmin[BM];
    __shared__ float    pn[128];

    int t  = threadIdx.x;
    int tm = t >> 4;          // 0..15 -> rows 4tm..4tm+3
    int tn = t & 15;          // 0..15 -> cols 8tn..8tn+7
    int m0 = blockIdx.x * BM;

    if (t < BM)  { rown[t] = 0.f; covmin[t] = 0x7F7F7F7Fu; }
    if (t < 128) { colmin[t] = 0x7F7F7F7Fu; pn[t] = pnorm[t]; }
    __syncthreads();

    float acc[4][8] = {};

    for (int k0 = 0; k0 < dd; k0 += BK) {
        // A tile: thread loads rows t/8 and t/8+32, float4 at col 4*(t&7)
        {
            int r  = t >> 3;
            int c4 = t & 7;
            float4 v = *(const float4*)(emb + (size_t)(m0 + r) * dd + k0 + c4 * 4);
            *(float4*)(&As[r][c4 * 4]) = v;
            atomicAdd(&rown[r], v.x * v.x + v.y * v.y + v.z * v.z + v.w * v.w);
            int r2 = r + 32;
            float4 v2 = *(const float4*)(emb + (size_t)(m0 + r2) * dd + k0 + c4 * 4);
            *(float4*)(&As[r2][c4 * 4]) = v2;
            atomicAdd(&rown[r2], v2.x * v2.x + v2.y * v2.y + v2.z * v2.z + v2.w * v2.w);
        }
        // B tile (transposed store): proto[p][k0+..] -> Bs[kk][p]
        {
            int c4    = t & 7;
            int pbase = t >> 3;
            #pragma unroll
            for (int g = 0; g < 4; ++g) {
                int p = pbase + g * 32;
                float4 v = *(const float4*)(proto + (size_t)p * dd + k0 + c4 * 4);
                Bs[c4 * 4 + 0][p] = v.x;
                Bs[c4 * 4 + 1][p] = v.y;
                Bs[c4 * 4 + 2][p] = v.z;
                Bs[c4 * 4 + 3][p] = v.w;
            }
        }
        __syncthreads();
        #pragma unroll 8
        for (int kk = 0; kk < BK; ++kk) {
            float a0 = As[4 * tm + 0][kk];
            float a1 = As[4 * tm + 1][kk];
            float a2 = As[4 * tm + 2][kk];
            float a3 = As[4 * tm + 3][kk];
            float4 b0 = *(const float4*)(&Bs[kk][8 * tn]);
            float4 b1 = *(const float4*)(&Bs[kk][8 * tn + 4]);
            float bs[8] = {b0.x, b0.y, b0.z, b0.w, b1.x, b1.y, b1.z, b1.w};
            float as[4] = {a0, a1, a2, a3};
            #pragma unroll
            for (int j = 0; j < 4; ++j)
                #pragma unroll
                for (int c = 0; c < 8; ++c)
                    acc[j][c] = fmaf(as[j], bs[c], acc[j][c]);
        }
        __syncthreads();
    }

    // epilogue: dist = sqrt(clip(nx + ny - 2*dot)), then row/col mins
    float pnl[8];
    #pragma unroll
    for (int c = 0; c < 8; ++c) pnl[c] = pn[8 * tn + c];
    #pragma unroll
    for (int j = 0; j < 4; ++j) {
        int r = 4 * tm + j;
        float nx = rown[r];
        float rmin = 3.0e38f;
        #pragma unroll
        for (int c = 0; c < 8; ++c) {
            float sq = nx + pnl[c] - 2.f * acc[j][c];
            float dist = sqrtf(fmaxf(sq, FEPS));
            acc[j][c] = dist;
            rmin = fminf(rmin, dist);
        }
        atomicMin(&covmin[r], __float_as_uint(rmin));
    }
    #pragma unroll
    for (int c = 0; c < 8; ++c) {
        float cmin = fminf(fminf(acc[0][c], acc[1][c]), fminf(acc[2][c], acc[3][c]));
        atomicMin(&colmin[8 * tn + c], __float_as_uint(cmin));
    }
    __syncthreads();
    if (t < 64) {
        float cv = __uint_as_float(covmin[t]);
        #pragma unroll
        for (int o = 32; o; o >>= 1) cv += __shfl_xor(cv, o);
        if (t == 0) atomicAdd(cov_out, cv);
    }
    if (t < 128) atomicMin(&proto_min[t], colmin[t]);
}

// ---------------- final combine --------------------------------------------
__global__ void final_kernel(const float* __restrict__ ws,
                             const unsigned* __restrict__ pmin,
                             float* __restrict__ out, int B, int D, int P) {
    float sim = 0.f;
    for (int i = 0; i < P; ++i) sim += __uint_as_float(pmin[i]);
    float ce  = ws[0] / (float)B;
    float mse = ws[1] / ((float)B * (float)D);
    out[0] = ce + 0.05f * mse + 0.05f * ws[2] + 0.05f * (sim / (float)P)
           + 0.05f * (ws[3] / (float)B);
}

extern "C" void kernel_launch(void* const* d_in, const int* in_sizes, int n_in,
                              void* d_out, int out_size, void* d_ws, size_t ws_size,
                              hipStream_t stream) {
    const float* pred  = (const float*)d_in[0];
    const float* recon = (const float*)d_in[1];
    const float* data  = (const float*)d_in[2];
    const float* emb   = (const float*)d_in[3];
    const float* proto = (const float*)d_in[4];
    const int*   lab   = (const int*)d_in[5];
    float* out = (float*)d_out;

    int B  = in_sizes[5];            // 32768
    int C  = in_sizes[0] / B;        // 100
    int D  = in_sizes[1] / B;        // 1024
    int dd = in_sizes[3] / B;        // 512
    int P  = in_sizes[4] / dd;       // 128

    float* ws = (float*)d_ws;
    // ws layout: [0]=ce_sum [1]=mse_sum [2]=div_sum [3]=cov_sum
    //            [4..4+P)  = proto_min (uint bits, init huge)
    //            [4+P..4+2P) = proto norms (written by div_kernel)
    hipMemsetAsync(ws, 0, 4 * sizeof(float), stream);
    hipMemsetAsync(ws + 4, 0x7F, P * sizeof(float), stream);
    unsigned* proto_min = (unsigned*)(ws + 4);
    float*    pnorm     = ws + 4 + P;

    ce_kernel<<<256, 256, 0, stream>>>(pred, lab, ws + 0, B, C, B / 1024);
    int n4 = (B * D) / 4;
    mse_kernel<<<1024, 256, 0, stream>>>((const float4*)recon, (const float4*)data,
                                         ws + 1, n4);
    div_kernel<<<P, 128, 0, stream>>>(proto, ws + 2, pnorm, P, dd);
    dist_kernel<<<B / BM, 256, 0, stream>>>(emb, proto, pnorm, proto_min, ws + 3, dd);
    final_kernel<<<1, 1, 0, stream>>>(ws, proto_min, out, B, D, P);
}

// Round 2
// 175.910 us; speedup vs baseline: 1.2374x; 1.2374x over previous
//
#include <hip/hip_runtime.h>
#include <hip/hip_bf16.h>

// ---------------------------------------------------------------------------
// total = CE(pred, labels)
//       + 0.05 * MSE(recon, data)
//       + 0.05 * sum_{j<k} max(0, 1 - ||p_j - p_k||)^2
//       + 0.05 * sum_p min_b dist(e_b, p) / P
//       + 0.05 * sum_b min_p dist(e_b, p) / B
// dist via ||x||^2 + ||y||^2 - 2 x.y, clipped at 1e-12, sqrt.
// dist GEMM (32768x128x512) done with bf16 MFMA; norms stay fp32.
// ---------------------------------------------------------------------------

constexpr float FEPS = 1e-12f;
constexpr float DMIN = 1.0f;

typedef unsigned short ushort_t;
typedef __attribute__((ext_vector_type(8))) short bf16x8;
typedef __attribute__((ext_vector_type(8))) unsigned short u16x8;
typedef __attribute__((ext_vector_type(4))) unsigned short u16x4;
typedef __attribute__((ext_vector_type(16))) float f32x16;

__device__ __forceinline__ unsigned short f2b(float f) {
    unsigned u = __float_as_uint(f);
    u += 0x7FFFu + ((u >> 16) & 1u);   // RNE to bf16
    return (unsigned short)(u >> 16);
}

// ---------------- CE: one wave per row (C=100 <= 128) ----------------------
__global__ __launch_bounds__(256) void ce_kernel(const float* __restrict__ pred,
                                                 const int* __restrict__ lab,
                                                 float* __restrict__ ce_out,
                                                 int B, int C, int rows_per_wave) {
    int lane = threadIdx.x & 63;
    int w    = threadIdx.x >> 6;
    int wid  = blockIdx.x * 4 + w;
    float acc = 0.f;
    for (int i = 0; i < rows_per_wave; ++i) {
        int row = wid * rows_per_wave + i;
        if (row >= B) break;
        const float* p = pred + (size_t)row * C;
        float v1 = (lane < C)      ? p[lane]      : -3.0e38f;
        float v2 = (lane + 64 < C) ? p[lane + 64] : -3.0e38f;
        float m = fmaxf(v1, v2);
        #pragma unroll
        for (int o = 32; o; o >>= 1) m = fmaxf(m, __shfl_xor(m, o));
        float s = ((lane < C) ? __expf(v1 - m) : 0.f)
                + ((lane + 64 < C) ? __expf(v2 - m) : 0.f);
        #pragma unroll
        for (int o = 32; o; o >>= 1) s += __shfl_xor(s, o);
        float lv = p[lab[row]];
        acc += m + __logf(s) - lv;
    }
    __shared__ float sred[4];
    if (lane == 0) sred[w] = acc;
    __syncthreads();
    if (threadIdx.x == 0) atomicAdd(ce_out, sred[0] + sred[1] + sred[2] + sred[3]);
}

// ---------------- MSE: float4 grid-stride ----------------------------------
__global__ __launch_bounds__(256) void mse_kernel(const float4* __restrict__ r,
                                                  const float4* __restrict__ d,
                                                  float* __restrict__ out, int n4) {
    int idx    = blockIdx.x * blockDim.x + threadIdx.x;
    int stride = gridDim.x * blockDim.x;
    float acc = 0.f;
    for (int i = idx; i < n4; i += stride) {
        float4 a = r[i], b = d[i];
        float dx = a.x - b.x, dy = a.y - b.y, dz = a.z - b.z, dw = a.w - b.w;
        acc = fmaf(dx, dx, acc);
        acc = fmaf(dy, dy, acc);
        acc = fmaf(dz, dz, acc);
        acc = fmaf(dw, dw, acc);
    }
    #pragma unroll
    for (int o = 32; o; o >>= 1) acc += __shfl_xor(acc, o);
    __shared__ float sred[4];
    int lane = threadIdx.x & 63, w = threadIdx.x >> 6;
    if (lane == 0) sred[w] = acc;
    __syncthreads();
    if (threadIdx.x == 0) atomicAdd(out, sred[0] + sred[1] + sred[2] + sred[3]);
}

// ---------------- Prototype diversity --------------------------------------
__global__ __launch_bounds__(128) void div_kernel(const float* __restrict__ proto,
                                                  float* __restrict__ div_out,
                                                  int P, int dd) {
    __shared__ float pp[1024];
    __shared__ float spp;
    int p = blockIdx.x, q = threadIdx.x;
    for (int k = q; k < dd; k += blockDim.x) pp[k] = proto[(size_t)p * dd + k];
    __syncthreads();
    const float4* pq4 = (const float4*)(proto + (size_t)q * dd);
    const float4* pp4 = (const float4*)pp;
    float dot = 0.f, qq = 0.f;
    for (int k4 = 0; k4 < dd / 4; ++k4) {
        float4 v = pq4[k4];
        float4 u = pp4[k4];
        dot = fmaf(u.x, v.x, dot); dot = fmaf(u.y, v.y, dot);
        dot = fmaf(u.z, v.z, dot); dot = fmaf(u.w, v.w, dot);
        qq  = fmaf(v.x, v.x, qq);  qq  = fmaf(v.y, v.y, qq);
        qq  = fmaf(v.z, v.z, qq);  qq  = fmaf(v.w, v.w, qq);
    }
    if (q == p) spp = qq;
    __syncthreads();
    float h2 = 0.f;
    if (q > p) {
        float sq = spp + qq - 2.f * dot;
        float dist = sqrtf(fmaxf(sq, FEPS));
        float h = fmaxf(0.f, DMIN - dist);
        h2 = h * h;
    }
    #pragma unroll
    for (int o = 32; o; o >>= 1) h2 += __shfl_xor(h2, o);
    __shared__ float sred[2];
    if ((threadIdx.x & 63) == 0) sred[threadIdx.x >> 6] = h2;
    __syncthreads();
    if (threadIdx.x == 0) atomicAdd(div_out, sred[0] + sred[1]);
}

// ---------------- proto fp32 -> bf16 (linear [p][k]) + norms ----------------
__global__ __launch_bounds__(128) void conv_kernel(const float* __restrict__ proto,
                                                   ushort_t* __restrict__ pB,
                                                   float* __restrict__ pnorm) {
    int p = blockIdx.x, q = threadIdx.x;
    float4 v = ((const float4*)(proto + (size_t)p * 512))[q];
    u16x4 o = { f2b(v.x), f2b(v.y), f2b(v.z), f2b(v.w) };
    *(u16x4*)(pB + (size_t)p * 512 + q * 4) = o;
    float s = v.x * v.x + v.y * v.y + v.z * v.z + v.w * v.w;
    #pragma unroll
    for (int off = 32; off; off >>= 1) s += __shfl_xor(s, off);
    __shared__ float sr[2];
    if ((q & 63) == 0) sr[q >> 6] = s;
    __syncthreads();
    if (q == 0) pnorm[p] = sr[0] + sr[1];
}

// ---------------- dist GEMM (MFMA bf16) + row/col mins ----------------------
// M=32768, N=128(P), K=512. Block: 256 thr = 4 waves; BM=64 rows; BK=64.
// Wave w: row-tile wr=w>>1 (32 rows), col-half wc=w&1 (2x 32-proto tiles).
// LDS images XOR-swizzled per 16B granule: byte = row*128 + ((g ^ (row&7))<<4).
template<bool PRECONV>
__global__ __launch_bounds__(256) void dist_kernel(const float* __restrict__ emb,
                                                   const float* __restrict__ proto,
                                                   const ushort_t* __restrict__ pB,
                                                   const float* __restrict__ pnormG,
                                                   unsigned* __restrict__ proto_min,
                                                   float* __restrict__ cov_out) {
    __shared__ __attribute__((aligned(16))) char AsB[2 * 8192];    // 64 x 64 bf16
    __shared__ __attribute__((aligned(16))) char BsB[2 * 16384];   // 128 x 64 bf16
    __shared__ float    rownL[64];
    __shared__ float    pnL[128];
    __shared__ unsigned rowminL[64];
    __shared__ unsigned colminL[128];

    const int t  = threadIdx.x;
    const int m0 = blockIdx.x * 64;

    if (t < 64)  { rownL[t] = 0.f; rowminL[t] = 0x7F7F7F7Fu; }
    if (t < 128) { colminL[t] = 0x7F7F7F7Fu; pnL[t] = PRECONV ? pnormG[t] : 0.f; }

    // staging assignment
    const int ra = t >> 2, qa = t & 3;   // A: row ra, 16 floats at k'=qa*16
    const int pb = t >> 1, hb = t & 1;   // B: proto pb, 32 k at k'=hb*32
    const int raz = ra & 7, pbz = pb & 7;

    const float4* aG  = (const float4*)(emb + (size_t)(m0 + ra) * 512 + qa * 16);
    const u16x8*  bG  = (const u16x8*)(pB) + (size_t)pb * 64 + hb * 4;       // PRECONV
    const float4* bGf = (const float4*)(proto + (size_t)pb * 512 + hb * 32); // fallback

    // fragment-read geometry
    const int lane = t & 63, wv = t >> 6;
    const int wr = wv >> 1, wc = wv & 1;
    const int lo = lane & 31, hi = lane >> 5;
    const int arow = wr * 32 + lo;
    const int arz  = arow & 7;
    const int p0 = wc * 64 + lo, p1 = p0 + 32;
    const int pz = p0 & 7;                     // p1&7 == p0&7

    // prologue: load chunk 0
    float4 av0 = aG[0], av1 = aG[1], av2 = aG[2], av3 = aG[3];
    u16x8  bv0, bv1, bv2, bv3;
    float4 bf0, bf1, bf2, bf3, bf4, bf5, bf6, bf7;
    if constexpr (PRECONV) { bv0 = bG[0]; bv1 = bG[1]; bv2 = bG[2]; bv3 = bG[3]; }
    else { bf0 = bGf[0]; bf1 = bGf[1]; bf2 = bGf[2]; bf3 = bGf[3];
           bf4 = bGf[4]; bf5 = bGf[5]; bf6 = bGf[6]; bf7 = bGf[7]; }

    f32x16 acc0 = {}, acc1 = {};

    for (int c = 0; c < 8; ++c) {
        const int buf = c & 1;
        char* Aw = AsB + buf * 8192  + ra * 128;
        char* Bw = BsB + buf * 16384 + pb * 128;

        // ---- write staged regs -> LDS (+ fp32 norms) ----
        {
            float nx = 0.f;
            nx = fmaf(av0.x, av0.x, nx); nx = fmaf(av0.y, av0.y, nx);
            nx = fmaf(av0.z, av0.z, nx); nx = fmaf(av0.w, av0.w, nx);
            nx = fmaf(av1.x, av1.x, nx); nx = fmaf(av1.y, av1.y, nx);
            nx = fmaf(av1.z, av1.z, nx); nx = fmaf(av1.w, av1.w, nx);
            nx = fmaf(av2.x, av2.x, nx); nx = fmaf(av2.y, av2.y, nx);
            nx = fmaf(av2.z, av2.z, nx); nx = fmaf(av2.w, av2.w, nx);
            nx = fmaf(av3.x, av3.x, nx); nx = fmaf(av3.y, av3.y, nx);
            nx = fmaf(av3.z, av3.z, nx); nx = fmaf(av3.w, av3.w, nx);
            atomicAdd(&rownL[ra], nx);
            u16x8 w0 = { f2b(av0.x), f2b(av0.y), f2b(av0.z), f2b(av0.w),
                         f2b(av1.x), f2b(av1.y), f2b(av1.z), f2b(av1.w) };
            u16x8 w1 = { f2b(av2.x), f2b(av2.y), f2b(av2.z), f2b(av2.w),
                         f2b(av3.x), f2b(av3.y), f2b(av3.z), f2b(av3.w) };
            *(u16x8*)(Aw + (((qa * 2 + 0) ^ raz) << 4)) = w0;
            *(u16x8*)(Aw + (((qa * 2 + 1) ^ raz) << 4)) = w1;

            if constexpr (PRECONV) {
                *(u16x8*)(Bw + (((hb * 4 + 0) ^ pbz) << 4)) = bv0;
                *(u16x8*)(Bw + (((hb * 4 + 1) ^ pbz) << 4)) = bv1;
                *(u16x8*)(Bw + (((hb * 4 + 2) ^ pbz) << 4)) = bv2;
                *(u16x8*)(Bw + (((hb * 4 + 3) ^ pbz) << 4)) = bv3;
            } else {
                float pns = 0.f;
                pns = fmaf(bf0.x, bf0.x, pns); pns = fmaf(bf0.y, bf0.y, pns);
                pns = fmaf(bf0.z, bf0.z, pns); pns = fmaf(bf0.w, bf0.w, pns);
                pns = fmaf(bf1.x, bf1.x, pns); pns = fmaf(bf1.y, bf1.y, pns);
                pns = fmaf(bf1.z, bf1.z, pns); pns = fmaf(bf1.w, bf1.w, pns);
                pns = fmaf(bf2.x, bf2.x, pns); pns = fmaf(bf2.y, bf2.y, pns);
                pns = fmaf(bf2.z, bf2.z, pns); pns = fmaf(bf2.w, bf2.w, pns);
                pns = fmaf(bf3.x, bf3.x, pns); pns = fmaf(bf3.y, bf3.y, pns);
                pns = fmaf(bf3.z, bf3.z, pns); pns = fmaf(bf3.w, bf3.w, pns);
                pns = fmaf(bf4.x, bf4.x, pns); pns = fmaf(bf4.y, bf4.y, pns);
                pns = fmaf(bf4.z, bf4.z, pns); pns = fmaf(bf4.w, bf4.w, pns);
                pns = fmaf(bf5.x, bf5.x, pns); pns = fmaf(bf5.y, bf5.y, pns);
                pns = fmaf(bf5.z, bf5.z, pns); pns = fmaf(bf5.w, bf5.w, pns);
                pns = fmaf(bf6.x, bf6.x, pns); pns = fmaf(bf6.y, bf6.y, pns);
                pns = fmaf(bf6.z, bf6.z, pns); pns = fmaf(bf6.w, bf6.w, pns);
                pns = fmaf(bf7.x, bf7.x, pns); pns = fmaf(bf7.y, bf7.y, pns);
                pns = fmaf(bf7.z, bf7.z, pns); pns = fmaf(bf7.w, bf7.w, pns);
                atomicAdd(&pnL[pb], pns);
                u16x8 x0 = { f2b(bf0.x), f2b(bf0.y), f2b(bf0.z), f2b(bf0.w),
                             f2b(bf1.x), f2b(bf1.y), f2b(bf1.z), f2b(bf1.w) };
                u16x8 x1 = { f2b(bf2.x), f2b(bf2.y), f2b(bf2.z), f2b(bf2.w),
                             f2b(bf3.x), f2b(bf3.y), f2b(bf3.z), f2b(bf3.w) };
                u16x8 x2 = { f2b(bf4.x), f2b(bf4.y), f2b(bf4.z), f2b(bf4.w),
                             f2b(bf5.x), f2b(bf5.y), f2b(bf5.z), f2b(bf5.w) };
                u16x8 x3 = { f2b(bf6.x), f2b(bf6.y), f2b(bf6.z), f2b(bf6.w),
                             f2b(bf7.x), f2b(bf7.y), f2b(bf7.z), f2b(bf7.w) };
                *(u16x8*)(Bw + (((hb * 4 + 0) ^ pbz) << 4)) = x0;
                *(u16x8*)(Bw + (((hb * 4 + 1) ^ pbz) << 4)) = x1;
                *(u16x8*)(Bw + (((hb * 4 + 2) ^ pbz) << 4)) = x2;
                *(u16x8*)(Bw + (((hb * 4 + 3) ^ pbz) << 4)) = x3;
            }
        }
        __syncthreads();
        // ---- prefetch next chunk into regs ----
        if (c < 7) {
            av0 = aG[(c + 1) * 16 + 0]; av1 = aG[(c + 1) * 16 + 1];
            av2 = aG[(c + 1) * 16 + 2]; av3 = aG[(c + 1) * 16 + 3];
            if constexpr (PRECONV) {
                bv0 = bG[(c + 1) * 8 + 0]; bv1 = bG[(c + 1) * 8 + 1];
                bv2 = bG[(c + 1) * 8 + 2]; bv3 = bG[(c + 1) * 8 + 3];
            } else {
                bf0 = bGf[(c + 1) * 16 + 0]; bf1 = bGf[(c + 1) * 16 + 1];
                bf2 = bGf[(c + 1) * 16 + 2]; bf3 = bGf[(c + 1) * 16 + 3];
                bf4 = bGf[(c + 1) * 16 + 4]; bf5 = bGf[(c + 1) * 16 + 5];
                bf6 = bGf[(c + 1) * 16 + 6]; bf7 = bGf[(c + 1) * 16 + 7];
            }
        }
        // ---- MFMA on current chunk ----
        const char* Ar = AsB + buf * 8192  + arow * 128;
        const char* Br0 = BsB + buf * 16384 + p0 * 128;
        const char* Br1 = BsB + buf * 16384 + p1 * 128;
        #pragma unroll
        for (int s = 0; s < 4; ++s) {
            const int g = (s * 2 + hi);
            bf16x8 af = *(const bf16x8*)(Ar  + ((g ^ arz) << 4));
            bf16x8 b0 = *(const bf16x8*)(Br0 + ((g ^ pz)  << 4));
            bf16x8 b1 = *(const bf16x8*)(Br1 + ((g ^ pz)  << 4));
            acc0 = __builtin_amdgcn_mfma_f32_32x32x16_bf16(af, b0, acc0, 0, 0, 0);
            acc1 = __builtin_amdgcn_mfma_f32_32x32x16_bf16(af, b1, acc1, 0, 0, 0);
        }
    }

    // ---- epilogue: dist + mins (C/D: col=lane&31, row=(r&3)+8*(r>>2)+4*hi) ----
    const float pn0 = pnL[p0], pn1 = pnL[p1];
    float cmin0 = 3.0e38f, cmin1 = 3.0e38f;
    #pragma unroll
    for (int r = 0; r < 16; ++r) {
        const int row = wr * 32 + (r & 3) + 8 * (r >> 2) + 4 * hi;
        const float nx = rownL[row];
        float d0 = sqrtf(fmaxf(nx + pn0 - 2.f * acc0[r], FEPS));
        float d1 = sqrtf(fmaxf(nx + pn1 - 2.f * acc1[r], FEPS));
        cmin0 = fminf(cmin0, d0);
        cmin1 = fminf(cmin1, d1);
        atomicMin(&rowminL[row], __float_as_uint(fminf(d0, d1)));
    }
    atomicMin(&colminL[p0], __float_as_uint(cmin0));
    atomicMin(&colminL[p1], __float_as_uint(cmin1));
    __syncthreads();

    if (t < 64) {
        float cv = __uint_as_float(rowminL[t]);
        #pragma unroll
        for (int o = 32; o; o >>= 1) cv += __shfl_xor(cv, o);
        if (t == 0) atomicAdd(cov_out, cv);
    }
    if (t < 128) atomicMin(&proto_min[t], colminL[t]);
}

// ---------------- final combine --------------------------------------------
__global__ void final_kernel(const float* __restrict__ ws,
                             const unsigned* __restrict__ pmin,
                             float* __restrict__ out, int B, int D, int P) {
    float sim = 0.f;
    for (int i = 0; i < P; ++i) sim += __uint_as_float(pmin[i]);
    float ce  = ws[0] / (float)B;
    float mse = ws[1] / ((float)B * (float)D);
    out[0] = ce + 0.05f * mse + 0.05f * ws[2] + 0.05f * (sim / (float)P)
           + 0.05f * (ws[3] / (float)B);
}

extern "C" void kernel_launch(void* const* d_in, const int* in_sizes, int n_in,
                              void* d_out, int out_size, void* d_ws, size_t ws_size,
                              hipStream_t stream) {
    const float* pred  = (const float*)d_in[0];
    const float* recon = (const float*)d_in[1];
    const float* data  = (const float*)d_in[2];
    const float* emb   = (const float*)d_in[3];
    const float* proto = (const float*)d_in[4];
    const int*   lab   = (const int*)d_in[5];
    float* out = (float*)d_out;

    int B  = in_sizes[5];            // 32768
    int C  = in_sizes[0] / B;        // 100
    int D  = in_sizes[1] / B;        // 1024
    int dd = in_sizes[3] / B;        // 512
    int P  = in_sizes[4] / dd;       // 128

    float* ws = (float*)d_ws;
    // ws layout: [0]=ce [1]=mse [2]=div [3]=cov ; [4..131]=proto_min bits ;
    //            [132..259]=pnorm ; byte 1280.. : pB bf16 [128][512]
    unsigned* proto_min = (unsigned*)(ws + 4);
    float*    pnorm     = ws + 132;
    ushort_t* pB        = (ushort_t*)((char*)d_ws + 1280);
    bool preconv = ws_size >= (size_t)(1280 + 128 * 512 * 2);

    hipMemsetAsync(ws, 0, 4 * sizeof(float), stream);
    hipMemsetAsync(ws + 4, 0x7F, P * sizeof(unsigned), stream);

    ce_kernel<<<256, 256, 0, stream>>>(pred, lab, ws + 0, B, C, B / 1024);
    int n4 = (B * D) / 4;
    mse_kernel<<<2048, 256, 0, stream>>>((const float4*)recon, (const float4*)data,
                                         ws + 1, n4);
    div_kernel<<<P, 128, 0, stream>>>(proto, ws + 2, P, dd);
    if (preconv) {
        conv_kernel<<<128, 128, 0, stream>>>(proto, pB, pnorm);
        dist_kernel<true><<<B / 64, 256, 0, stream>>>(emb, proto, pB, pnorm,
                                                      proto_min, ws + 3);
    } else {
        dist_kernel<false><<<B / 64, 256, 0, stream>>>(emb, proto, nullptr, nullptr,
                                                       proto_min, ws + 3);
    }
    final_kernel<<<1, 1, 0, stream>>>(ws, proto_min, out, B, D, P);
}

// Round 3
// 117.104 us; speedup vs baseline: 1.8588x; 1.5022x over previous
//
#include <hip/hip_runtime.h>
#include <hip/hip_bf16.h>

// ---------------------------------------------------------------------------
// total = CE(pred, labels)
//       + 0.05 * MSE(recon, data)
//       + 0.05 * sum_{j<k} max(0, 1 - ||p_j - p_k||)^2
//       + 0.05 * sum_p min_b dist(e_b, p) / P
//       + 0.05 * sum_b min_p dist(e_b, p) / B
// dist GEMM (32768x128x512) via bf16 MFMA; norms fp32.
// Round 3: single fused kernel (dist | mse | ce | div block ranges) so MSE's
// HBM streaming overlaps dist's compute; MSE gets 4-wide ILP.
// ---------------------------------------------------------------------------

constexpr float FEPS = 1e-12f;
constexpr float DMIN = 1.0f;

#define NB_DIST 512
#define NB_MSE  1024
#define NB_CE   256
#define NB_DIV  128

typedef unsigned short ushort_t;
typedef __attribute__((ext_vector_type(8))) short bf16x8;
typedef __attribute__((ext_vector_type(8))) unsigned short u16x8;
typedef __attribute__((ext_vector_type(4))) unsigned short u16x4;
typedef __attribute__((ext_vector_type(16))) float f32x16;

__device__ __forceinline__ unsigned short f2b(float f) {
    unsigned u = __float_as_uint(f);
    u += 0x7FFFu + ((u >> 16) & 1u);   // RNE to bf16
    return (unsigned short)(u >> 16);
}

union SmemU {
    struct {
        char     As[2 * 8192];     // 64 x 64 bf16, dbuf, XOR-swizzled
        char     Bs[2 * 16384];    // 128 x 64 bf16, dbuf, XOR-swizzled
        float    rown[64];
        float    pn[128];
        unsigned rowmin[64];
        unsigned colmin[128];
    } dist;
    struct { float pp[512]; float spp; float sred[4]; } div;
    struct { float sred[4]; } red;
};

// ---------------- proto fp32 -> bf16 (linear [p][k]) + norms ----------------
__global__ __launch_bounds__(128) void conv_kernel(const float* __restrict__ proto,
                                                   ushort_t* __restrict__ pB,
                                                   float* __restrict__ pnorm) {
    int p = blockIdx.x, q = threadIdx.x;
    float4 v = ((const float4*)(proto + (size_t)p * 512))[q];
    u16x4 o = { f2b(v.x), f2b(v.y), f2b(v.z), f2b(v.w) };
    *(u16x4*)(pB + (size_t)p * 512 + q * 4) = o;
    float s = v.x * v.x + v.y * v.y + v.z * v.z + v.w * v.w;
    #pragma unroll
    for (int off = 32; off; off >>= 1) s += __shfl_xor(s, off);
    __shared__ float sr[2];
    if ((q & 63) == 0) sr[q >> 6] = s;
    __syncthreads();
    if (q == 0) pnorm[p] = sr[0] + sr[1];
}

// ---------------- dist body (verified round-2 structure + barrier fix) ------
template<bool PRECONV>
__device__ __forceinline__ void dist_body(SmemU& sm, int bid,
                                          const float* __restrict__ emb,
                                          const float* __restrict__ proto,
                                          const ushort_t* __restrict__ pB,
                                          const float* __restrict__ pnormG,
                                          unsigned* __restrict__ proto_min,
                                          float* __restrict__ cov_out) {
    char*     AsB     = sm.dist.As;
    char*     BsB     = sm.dist.Bs;
    float*    rownL   = sm.dist.rown;
    float*    pnL     = sm.dist.pn;
    unsigned* rowminL = sm.dist.rowmin;
    unsigned* colminL = sm.dist.colmin;

    const int t  = threadIdx.x;
    const int m0 = bid * 64;

    if (t < 64)  { rownL[t] = 0.f; rowminL[t] = 0x7F7F7F7Fu; }
    if (t < 128) { colminL[t] = 0x7F7F7F7Fu; pnL[t] = PRECONV ? pnormG[t] : 0.f; }
    __syncthreads();   // init must land before staging atomics

    const int ra = t >> 2, qa = t & 3;
    const int pb = t >> 1, hb = t & 1;
    const int raz = ra & 7, pbz = pb & 7;

    const float4* aG  = (const float4*)(emb + (size_t)(m0 + ra) * 512 + qa * 16);
    const u16x8*  bG  = (const u16x8*)(pB) + (size_t)pb * 64 + hb * 4;
    const float4* bGf = (const float4*)(proto + (size_t)pb * 512 + hb * 32);

    const int lane = t & 63, wv = t >> 6;
    const int wr = wv >> 1, wc = wv & 1;
    const int lo = lane & 31, hi = lane >> 5;
    const int arow = wr * 32 + lo;
    const int arz  = arow & 7;
    const int p0 = wc * 64 + lo, p1 = p0 + 32;
    const int pz = p0 & 7;

    float4 av0 = aG[0], av1 = aG[1], av2 = aG[2], av3 = aG[3];
    u16x8  bv0, bv1, bv2, bv3;
    float4 bf0, bf1, bf2, bf3, bf4, bf5, bf6, bf7;
    if constexpr (PRECONV) { bv0 = bG[0]; bv1 = bG[1]; bv2 = bG[2]; bv3 = bG[3]; }
    else { bf0 = bGf[0]; bf1 = bGf[1]; bf2 = bGf[2]; bf3 = bGf[3];
           bf4 = bGf[4]; bf5 = bGf[5]; bf6 = bGf[6]; bf7 = bGf[7]; }

    f32x16 acc0 = {}, acc1 = {};

    for (int c = 0; c < 8; ++c) {
        const int buf = c & 1;
        char* Aw = AsB + buf * 8192  + ra * 128;
        char* Bw = BsB + buf * 16384 + pb * 128;
        {
            float nx = 0.f;
            nx = fmaf(av0.x, av0.x, nx); nx = fmaf(av0.y, av0.y, nx);
            nx = fmaf(av0.z, av0.z, nx); nx = fmaf(av0.w, av0.w, nx);
            nx = fmaf(av1.x, av1.x, nx); nx = fmaf(av1.y, av1.y, nx);
            nx = fmaf(av1.z, av1.z, nx); nx = fmaf(av1.w, av1.w, nx);
            nx = fmaf(av2.x, av2.x, nx); nx = fmaf(av2.y, av2.y, nx);
            nx = fmaf(av2.z, av2.z, nx); nx = fmaf(av2.w, av2.w, nx);
            nx = fmaf(av3.x, av3.x, nx); nx = fmaf(av3.y, av3.y, nx);
            nx = fmaf(av3.z, av3.z, nx); nx = fmaf(av3.w, av3.w, nx);
            atomicAdd(&rownL[ra], nx);
            u16x8 w0 = { f2b(av0.x), f2b(av0.y), f2b(av0.z), f2b(av0.w),
                         f2b(av1.x), f2b(av1.y), f2b(av1.z), f2b(av1.w) };
            u16x8 w1 = { f2b(av2.x), f2b(av2.y), f2b(av2.z), f2b(av2.w),
                         f2b(av3.x), f2b(av3.y), f2b(av3.z), f2b(av3.w) };
            *(u16x8*)(Aw + (((qa * 2 + 0) ^ raz) << 4)) = w0;
            *(u16x8*)(Aw + (((qa * 2 + 1) ^ raz) << 4)) = w1;

            if constexpr (PRECONV) {
                *(u16x8*)(Bw + (((hb * 4 + 0) ^ pbz) << 4)) = bv0;
                *(u16x8*)(Bw + (((hb * 4 + 1) ^ pbz) << 4)) = bv1;
                *(u16x8*)(Bw + (((hb * 4 + 2) ^ pbz) << 4)) = bv2;
                *(u16x8*)(Bw + (((hb * 4 + 3) ^ pbz) << 4)) = bv3;
            } else {
                float pns = 0.f;
                pns = fmaf(bf0.x, bf0.x, pns); pns = fmaf(bf0.y, bf0.y, pns);
                pns = fmaf(bf0.z, bf0.z, pns); pns = fmaf(bf0.w, bf0.w, pns);
                pns = fmaf(bf1.x, bf1.x, pns); pns = fmaf(bf1.y, bf1.y, pns);
                pns = fmaf(bf1.z, bf1.z, pns); pns = fmaf(bf1.w, bf1.w, pns);
                pns = fmaf(bf2.x, bf2.x, pns); pns = fmaf(bf2.y, bf2.y, pns);
                pns = fmaf(bf2.z, bf2.z, pns); pns = fmaf(bf2.w, bf2.w, pns);
                pns = fmaf(bf3.x, bf3.x, pns); pns = fmaf(bf3.y, bf3.y, pns);
                pns = fmaf(bf3.z, bf3.z, pns); pns = fmaf(bf3.w, bf3.w, pns);
                pns = fmaf(bf4.x, bf4.x, pns); pns = fmaf(bf4.y, bf4.y, pns);
                pns = fmaf(bf4.z, bf4.z, pns); pns = fmaf(bf4.w, bf4.w, pns);
                pns = fmaf(bf5.x, bf5.x, pns); pns = fmaf(bf5.y, bf5.y, pns);
                pns = fmaf(bf5.z, bf5.z, pns); pns = fmaf(bf5.w, bf5.w, pns);
                pns = fmaf(bf6.x, bf6.x, pns); pns = fmaf(bf6.y, bf6.y, pns);
                pns = fmaf(bf6.z, bf6.z, pns); pns = fmaf(bf6.w, bf6.w, pns);
                pns = fmaf(bf7.x, bf7.x, pns); pns = fmaf(bf7.y, bf7.y, pns);
                pns = fmaf(bf7.z, bf7.z, pns); pns = fmaf(bf7.w, bf7.w, pns);
                atomicAdd(&pnL[pb], pns);
                u16x8 x0 = { f2b(bf0.x), f2b(bf0.y), f2b(bf0.z), f2b(bf0.w),
                             f2b(bf1.x), f2b(bf1.y), f2b(bf1.z), f2b(bf1.w) };
                u16x8 x1 = { f2b(bf2.x), f2b(bf2.y), f2b(bf2.z), f2b(bf2.w),
                             f2b(bf3.x), f2b(bf3.y), f2b(bf3.z), f2b(bf3.w) };
                u16x8 x2 = { f2b(bf4.x), f2b(bf4.y), f2b(bf4.z), f2b(bf4.w),
                             f2b(bf5.x), f2b(bf5.y), f2b(bf5.z), f2b(bf5.w) };
                u16x8 x3 = { f2b(bf6.x), f2b(bf6.y), f2b(bf6.z), f2b(bf6.w),
                             f2b(bf7.x), f2b(bf7.y), f2b(bf7.z), f2b(bf7.w) };
                *(u16x8*)(Bw + (((hb * 4 + 0) ^ pbz) << 4)) = x0;
                *(u16x8*)(Bw + (((hb * 4 + 1) ^ pbz) << 4)) = x1;
                *(u16x8*)(Bw + (((hb * 4 + 2) ^ pbz) << 4)) = x2;
                *(u16x8*)(Bw + (((hb * 4 + 3) ^ pbz) << 4)) = x3;
            }
        }
        __syncthreads();
        if (c < 7) {
            av0 = aG[(c + 1) * 16 + 0]; av1 = aG[(c + 1) * 16 + 1];
            av2 = aG[(c + 1) * 16 + 2]; av3 = aG[(c + 1) * 16 + 3];
            if constexpr (PRECONV) {
                bv0 = bG[(c + 1) * 8 + 0]; bv1 = bG[(c + 1) * 8 + 1];
                bv2 = bG[(c + 1) * 8 + 2]; bv3 = bG[(c + 1) * 8 + 3];
            } else {
                bf0 = bGf[(c + 1) * 16 + 0]; bf1 = bGf[(c + 1) * 16 + 1];
                bf2 = bGf[(c + 1) * 16 + 2]; bf3 = bGf[(c + 1) * 16 + 3];
                bf4 = bGf[(c + 1) * 16 + 4]; bf5 = bGf[(c + 1) * 16 + 5];
                bf6 = bGf[(c + 1) * 16 + 6]; bf7 = bGf[(c + 1) * 16 + 7];
            }
        }
        const char* Ar  = AsB + buf * 8192  + arow * 128;
        const char* Br0 = BsB + buf * 16384 + p0 * 128;
        const char* Br1 = BsB + buf * 16384 + p1 * 128;
        #pragma unroll
        for (int s = 0; s < 4; ++s) {
            const int g = (s * 2 + hi);
            bf16x8 af = *(const bf16x8*)(Ar  + ((g ^ arz) << 4));
            bf16x8 b0 = *(const bf16x8*)(Br0 + ((g ^ pz)  << 4));
            bf16x8 b1 = *(const bf16x8*)(Br1 + ((g ^ pz)  << 4));
            acc0 = __builtin_amdgcn_mfma_f32_32x32x16_bf16(af, b0, acc0, 0, 0, 0);
            acc1 = __builtin_amdgcn_mfma_f32_32x32x16_bf16(af, b1, acc1, 0, 0, 0);
        }
    }

    const float pn0 = pnL[p0], pn1 = pnL[p1];
    float cmin0 = 3.0e38f, cmin1 = 3.0e38f;
    #pragma unroll
    for (int r = 0; r < 16; ++r) {
        const int row = wr * 32 + (r & 3) + 8 * (r >> 2) + 4 * hi;
        const float nx = rownL[row];
        float d0 = sqrtf(fmaxf(nx + pn0 - 2.f * acc0[r], FEPS));
        float d1 = sqrtf(fmaxf(nx + pn1 - 2.f * acc1[r], FEPS));
        cmin0 = fminf(cmin0, d0);
        cmin1 = fminf(cmin1, d1);
        atomicMin(&rowminL[row], __float_as_uint(fminf(d0, d1)));
    }
    atomicMin(&colminL[p0], __float_as_uint(cmin0));
    atomicMin(&colminL[p1], __float_as_uint(cmin1));
    __syncthreads();

    if (t < 64) {
        float cv = __uint_as_float(rowminL[t]);
        #pragma unroll
        for (int o = 32; o; o >>= 1) cv += __shfl_xor(cv, o);
        if (t == 0) atomicAdd(cov_out, cv);
    }
    if (t < 128) atomicMin(&proto_min[t], colminL[t]);
}

// ---------------- mse body (4-wide ILP) -------------------------------------
__device__ __forceinline__ void mse_body(SmemU& sm, int mb,
                                         const float4* __restrict__ r,
                                         const float4* __restrict__ d,
                                         float* __restrict__ out, int n4) {
    const int t = threadIdx.x;
    const int idx    = mb * 256 + t;
    const int stride = NB_MSE * 256;
    float acc0 = 0.f, acc1 = 0.f, acc2 = 0.f, acc3 = 0.f;
    int i = idx;
    for (; i + 3 * stride < n4; i += 4 * stride) {
        float4 a0 = r[i];
        float4 a1 = r[i + stride];
        float4 a2 = r[i + 2 * stride];
        float4 a3 = r[i + 3 * stride];
        float4 b0 = d[i];
        float4 b1 = d[i + stride];
        float4 b2 = d[i + 2 * stride];
        float4 b3 = d[i + 3 * stride];
        float e;
        e = a0.x - b0.x; acc0 = fmaf(e, e, acc0);
        e = a0.y - b0.y; acc0 = fmaf(e, e, acc0);
        e = a0.z - b0.z; acc0 = fmaf(e, e, acc0);
        e = a0.w - b0.w; acc0 = fmaf(e, e, acc0);
        e = a1.x - b1.x; acc1 = fmaf(e, e, acc1);
        e = a1.y - b1.y; acc1 = fmaf(e, e, acc1);
        e = a1.z - b1.z; acc1 = fmaf(e, e, acc1);
        e = a1.w - b1.w; acc1 = fmaf(e, e, acc1);
        e = a2.x - b2.x; acc2 = fmaf(e, e, acc2);
        e = a2.y - b2.y; acc2 = fmaf(e, e, acc2);
        e = a2.z - b2.z; acc2 = fmaf(e, e, acc2);
        e = a2.w - b2.w; acc2 = fmaf(e, e, acc2);
        e = a3.x - b3.x; acc3 = fmaf(e, e, acc3);
        e = a3.y - b3.y; acc3 = fmaf(e, e, acc3);
        e = a3.z - b3.z; acc3 = fmaf(e, e, acc3);
        e = a3.w - b3.w; acc3 = fmaf(e, e, acc3);
    }
    for (; i < n4; i += stride) {
        float4 a = r[i], b = d[i];
        float e;
        e = a.x - b.x; acc0 = fmaf(e, e, acc0);
        e = a.y - b.y; acc0 = fmaf(e, e, acc0);
        e = a.z - b.z; acc0 = fmaf(e, e, acc0);
        e = a.w - b.w; acc0 = fmaf(e, e, acc0);
    }
    float acc = (acc0 + acc1) + (acc2 + acc3);
    #pragma unroll
    for (int o = 32; o; o >>= 1) acc += __shfl_xor(acc, o);
    int lane = t & 63, w = t >> 6;
    if (lane == 0) sm.red.sred[w] = acc;
    __syncthreads();
    if (t == 0) atomicAdd(out, sm.red.sred[0] + sm.red.sred[1]
                             + sm.red.sred[2] + sm.red.sred[3]);
}

// ---------------- ce body ---------------------------------------------------
__device__ __forceinline__ void ce_body(SmemU& sm, int cb,
                                        const float* __restrict__ pred,
                                        const int* __restrict__ lab,
                                        float* __restrict__ ce_out,
                                        int B, int C) {
    const int rows_per_wave = B / (NB_CE * 4);
    int lane = threadIdx.x & 63;
    int w    = threadIdx.x >> 6;
    int wid  = cb * 4 + w;
    float acc = 0.f;
    for (int i = 0; i < rows_per_wave; ++i) {
        int row = wid * rows_per_wave + i;
        const float* p = pred + (size_t)row * C;
        float v1 = (lane < C)      ? p[lane]      : -3.0e38f;
        float v2 = (lane + 64 < C) ? p[lane + 64] : -3.0e38f;
        float m = fmaxf(v1, v2);
        #pragma unroll
        for (int o = 32; o; o >>= 1) m = fmaxf(m, __shfl_xor(m, o));
        float s = ((lane < C) ? __expf(v1 - m) : 0.f)
                + ((lane + 64 < C) ? __expf(v2 - m) : 0.f);
        #pragma unroll
        for (int o = 32; o; o >>= 1) s += __shfl_xor(s, o);
        float lv = p[lab[row]];
        acc += m + __logf(s) - lv;
    }
    if (lane == 0) sm.red.sred[w] = acc;
    __syncthreads();
    if (threadIdx.x == 0) atomicAdd(ce_out, sm.red.sred[0] + sm.red.sred[1]
                                          + sm.red.sred[2] + sm.red.sred[3]);
}

// ---------------- div body --------------------------------------------------
__device__ __forceinline__ void div_body(SmemU& sm, int p,
                                         const float* __restrict__ proto,
                                         float* __restrict__ div_out, int dd) {
    int q = threadIdx.x;
    bool act = q < 128;
    if (act) for (int k = q; k < dd; k += 128) sm.div.pp[k] = proto[(size_t)p * dd + k];
    __syncthreads();
    float dot = 0.f, qq = 0.f;
    if (act) {
        const float4* pq4 = (const float4*)(proto + (size_t)q * dd);
        const float4* pp4 = (const float4*)sm.div.pp;
        for (int k4 = 0; k4 < dd / 4; ++k4) {
            float4 v = pq4[k4];
            float4 u = pp4[k4];
            dot = fmaf(u.x, v.x, dot); dot = fmaf(u.y, v.y, dot);
            dot = fmaf(u.z, v.z, dot); dot = fmaf(u.w, v.w, dot);
            qq  = fmaf(v.x, v.x, qq);  qq  = fmaf(v.y, v.y, qq);
            qq  = fmaf(v.z, v.z, qq);  qq  = fmaf(v.w, v.w, qq);
        }
        if (q == p) sm.div.spp = qq;
    }
    __syncthreads();
    float h2 = 0.f;
    if (act && q > p) {
        float sq = sm.div.spp + qq - 2.f * dot;
        float dist = sqrtf(fmaxf(sq, FEPS));
        float h = fmaxf(0.f, DMIN - dist);
        h2 = h * h;
    }
    #pragma unroll
    for (int o = 32; o; o >>= 1) h2 += __shfl_xor(h2, o);
    if ((q & 63) == 0) sm.div.sred[q >> 6] = h2;
    __syncthreads();
    if (q == 0) atomicAdd(div_out, sm.div.sred[0] + sm.div.sred[1]
                                 + sm.div.sred[2] + sm.div.sred[3]);
}

// ---------------- fused kernel ----------------------------------------------
template<bool PRECONV>
__global__ __launch_bounds__(256) void fused_kernel(
        const float* __restrict__ pred, const int* __restrict__ lab,
        const float4* __restrict__ recon4, const float4* __restrict__ data4,
        const float* __restrict__ emb, const float* __restrict__ proto,
        const ushort_t* __restrict__ pB, const float* __restrict__ pnormG,
        float* __restrict__ ws, unsigned* __restrict__ proto_min,
        int B, int C, int n4, int dd) {
    __shared__ __attribute__((aligned(16))) SmemU sm;
    int bid = blockIdx.x;
    if (bid < NB_DIST) {
        dist_body<PRECONV>(sm, bid, emb, proto, pB, pnormG, proto_min, ws + 3);
    } else if (bid < NB_DIST + NB_MSE) {
        mse_body(sm, bid - NB_DIST, recon4, data4, ws + 1, n4);
    } else if (bid < NB_DIST + NB_MSE + NB_CE) {
        ce_body(sm, bid - NB_DIST - NB_MSE, pred, lab, ws + 0, B, C);
    } else {
        div_body(sm, bid - NB_DIST - NB_MSE - NB_CE, proto, ws + 2, dd);
    }
}

// ---------------- final combine ---------------------------------------------
__global__ void final_kernel(const float* __restrict__ ws,
                             const unsigned* __restrict__ pmin,
                             float* __restrict__ out, int B, int D, int P) {
    float sim = 0.f;
    for (int i = 0; i < P; ++i) sim += __uint_as_float(pmin[i]);
    float ce  = ws[0] / (float)B;
    float mse = ws[1] / ((float)B * (float)D);
    out[0] = ce + 0.05f * mse + 0.05f * ws[2] + 0.05f * (sim / (float)P)
           + 0.05f * (ws[3] / (float)B);
}

extern "C" void kernel_launch(void* const* d_in, const int* in_sizes, int n_in,
                              void* d_out, int out_size, void* d_ws, size_t ws_size,
                              hipStream_t stream) {
    const float* pred  = (const float*)d_in[0];
    const float* recon = (const float*)d_in[1];
    const float* data  = (const float*)d_in[2];
    const float* emb   = (const float*)d_in[3];
    const float* proto = (const float*)d_in[4];
    const int*   lab   = (const int*)d_in[5];
    float* out = (float*)d_out;

    int B  = in_sizes[5];            // 32768
    int C  = in_sizes[0] / B;        // 100
    int D  = in_sizes[1] / B;        // 1024
    int dd = in_sizes[3] / B;        // 512
    int P  = in_sizes[4] / dd;       // 128

    float* ws = (float*)d_ws;
    // ws layout: [0]=ce [1]=mse [2]=div [3]=cov ; [4..131]=proto_min bits ;
    //            [132..259]=pnorm ; byte 1280.. : pB bf16 [128][512]
    unsigned* proto_min = (unsigned*)(ws + 4);
    float*    pnorm     = ws + 132;
    ushort_t* pB        = (ushort_t*)((char*)d_ws + 1280);
    bool preconv = ws_size >= (size_t)(1280 + 128 * 512 * 2);

    hipMemsetAsync(ws, 0, 4 * sizeof(float), stream);
    hipMemsetAsync(ws + 4, 0x7F, P * sizeof(unsigned), stream);

    int n4 = (B * D) / 4;
    int grid = NB_DIST + NB_MSE + NB_CE + NB_DIV;
    if (preconv) {
        conv_kernel<<<128, 128, 0, stream>>>(proto, pB, pnorm);
        fused_kernel<true><<<grid, 256, 0, stream>>>(
            pred, lab, (const float4*)recon, (const float4*)data, emb, proto,
            pB, pnorm, ws, proto_min, B, C, n4, dd);
    } else {
        fused_kernel<false><<<grid, 256, 0, stream>>>(
            pred, lab, (const float4*)recon, (const float4*)data, emb, proto,
            nullptr, nullptr, ws, proto_min, B, C, n4, dd);
    }
    final_kernel<<<1, 1, 0, stream>>>(ws, proto_min, out, B, D, P);
}